// Round 2
// baseline (116.276 us; speedup 1.0000x reference)
//
#include <hip/hip_runtime.h>

// Problem constants (match reference)
#define RN     2000
#define NMAT   16          // B(4) * L(4)
#define NPROBE 8192        // multisection probes per matrix (2 per thread)
#define E2     160000.0f   // s^2 with s = (RN/RM)^2 = 400
#define DCONST 800.0f      // 2 * para0 * s
#define GERSH  810.0f      // Gershgorin radius 2*|e|=800 + slack

#define DIAG_PITCH 2048    // padded row pitch for diag in ws

// ---------------------------------------------------------------------------
// Kernel 1: build diagonal, reduce per-matrix min/max -> Gershgorin bounds.
// grid = NMAT blocks, 256 threads. m = b*4 + l.
// ---------------------------------------------------------------------------
__global__ void build_diag(const float* __restrict__ ptl,
                           float* __restrict__ diag,
                           float* __restrict__ bounds) {
    const int m = blockIdx.x;
    const int b = m >> 2;
    const int l = m & 3;
    const float ll1 = (float)(l * (l + 1));
    const float* p = ptl + b * RN;

    float lmin = 3.0e38f, lmax = -3.0e38f;
    for (int i = threadIdx.x; i < RN; i += blockDim.x) {
        float r = 0.05f * (float)(i + 1);          // linspace(RM/RN, RM, RN)
        float d = DCONST + p[i] + ll1 / (r * r);
        diag[m * DIAG_PITCH + i] = d;
        lmin = fminf(lmin, d);
        lmax = fmaxf(lmax, d);
    }

    __shared__ float smn[256], smx[256];
    smn[threadIdx.x] = lmin;
    smx[threadIdx.x] = lmax;
    __syncthreads();
    for (int s = 128; s > 0; s >>= 1) {
        if (threadIdx.x < s) {
            smn[threadIdx.x] = fminf(smn[threadIdx.x], smn[threadIdx.x + s]);
            smx[threadIdx.x] = fmaxf(smx[threadIdx.x], smx[threadIdx.x + s]);
        }
        __syncthreads();
    }
    if (threadIdx.x == 0) {
        bounds[2 * m + 0] = smn[0] - GERSH;
        bounds[2 * m + 1] = smx[0] + GERSH;
    }
}

// ---------------------------------------------------------------------------
// Kernel 2: Sturm counts at NPROBE uniform shifts per matrix.
// grid = NMAT * 16 blocks of 256 threads; each thread runs TWO independent
// probe chains (ILP to hide the dependent rcp->fma latency).
// Diag staged in LDS; all lanes read the same word per step (broadcast).
// count(x) = # negative pivots q_i of LDL(T - xI) = # eigenvalues < x.
// ---------------------------------------------------------------------------
__global__ void sturm_counts(const float* __restrict__ diag,
                             const float* __restrict__ bounds,
                             int* __restrict__ counts) {
    const int m     = blockIdx.x >> 4;   // 16 chunks/matrix
    const int chunk = blockIdx.x & 15;

    __shared__ float ds[RN];
    const float* dg = diag + m * DIAG_PITCH;
    for (int i = threadIdx.x; i < RN; i += blockDim.x)
        ds[i] = dg[i];
    __syncthreads();

    const float lo = bounds[2 * m + 0];
    const float hi = bounds[2 * m + 1];
    const float step = (hi - lo) / (float)(NPROBE + 1);

    const int p0 = chunk * 512 + threadIdx.x;        // probes p0 and p0+256
    const float x0 = lo + step * (float)(p0 + 1);
    const float x1 = lo + step * (float)(p0 + 256 + 1);

    float q0 = ds[0] - x0;
    float q1 = ds[0] - x1;
    int c0 = (int)(__float_as_uint(q0) >> 31);
    int c1 = (int)(__float_as_uint(q1) >> 31);
    // IEEE propagation handles zero pivots: q=0 -> rcp=+inf -> next q=-inf
    // (counted negative) -> rcp=-0 -> recurrence resumes cleanly. No NaN path.
    #pragma unroll 8
    for (int i = 1; i < RN; ++i) {
        const float d = ds[i];
        float r0 = __builtin_amdgcn_rcpf(q0);
        float r1 = __builtin_amdgcn_rcpf(q1);
        q0 = (d - x0) - E2 * r0;
        q1 = (d - x1) - E2 * r1;
        c0 += (int)(__float_as_uint(q0) >> 31);
        c1 += (int)(__float_as_uint(q1) >> 31);
    }
    counts[m * NPROBE + p0]       = c0;
    counts[m * NPROBE + p0 + 256] = c1;
}

// ---------------------------------------------------------------------------
// Kernel 3: for eigenvalue k of matrix m, binary-search the monotone count
// array for the first probe j with count >= k+1; eigenvalue lies in
// (x_{j-1}, x_j]; emit midpoint. Virtual endpoints: count(lo)=0, count(hi)=RN.
// ---------------------------------------------------------------------------
__global__ void select_eigs(const int* __restrict__ counts,
                            const float* __restrict__ bounds,
                            float* __restrict__ out) {
    const int g = blockIdx.x * blockDim.x + threadIdx.x;
    if (g >= NMAT * RN) return;
    const int m = g / RN;
    const int k = g - m * RN;

    const int* c = counts + m * NPROBE;
    const int kk = k + 1;
    int loi = 0, hii = NPROBE;          // answer in [0, NPROBE]
    while (loi < hii) {
        int mid = (loi + hii) >> 1;
        if (c[mid] >= kk) hii = mid; else loi = mid + 1;
    }
    const float lo = bounds[2 * m + 0];
    const float hi = bounds[2 * m + 1];
    const float step = (hi - lo) / (float)(NPROBE + 1);
    // bracket (x_{j-1}, x_j) with x_t = lo + (t+1)*step; midpoint:
    out[g] = lo + step * ((float)loi + 0.5f);
}

// ---------------------------------------------------------------------------
extern "C" void kernel_launch(void* const* d_in, const int* in_sizes, int n_in,
                              void* d_out, int out_size, void* d_ws, size_t ws_size,
                              hipStream_t stream) {
    const float* ptl = (const float*)d_in[0];   // (B=4, RN) f32
    float* out = (float*)d_out;                 // (4, 4, RN) f32 ascending

    float* diag   = (float*)d_ws;               // NMAT * DIAG_PITCH floats
    float* bounds = diag + NMAT * DIAG_PITCH;   // NMAT * 2 floats
    int*   counts = (int*)(bounds + 2 * NMAT);  // NMAT * NPROBE ints

    build_diag<<<NMAT, 256, 0, stream>>>(ptl, diag, bounds);
    sturm_counts<<<NMAT * 16, 256, 0, stream>>>(diag, bounds, counts);
    select_eigs<<<(NMAT * RN + 255) / 256, 256, 0, stream>>>(counts, bounds, out);
}

// Round 3
// 84.023 us; speedup vs baseline: 1.3839x; 1.3839x over previous
//
#include <hip/hip_runtime.h>
#include <math.h>

// Problem constants (match reference)
#define RN      2000
#define NMAT    16            // B(4) * L(4)
#define NCHUNK  16            // probe chunks per matrix
#define CSTRIDE 255           // chunk stride in probes (chunks overlap by 1 probe)
#define NPT     (NCHUNK*CSTRIDE + 1)   // 4081 distinct probes per matrix
#define E2      160000.0f     // s^2 with s = (RN/RM)^2 = 400
#define DCONST  800.0f        // 2 * para0 * s
#define GERSH   810.0f        // Gershgorin radius 2*|e|=800 + slack
#define NPAD    2016          // RN padded to 8*252; entries >= RN set to +INF
#define NGRP    251           // ceil(2008/8): iterate i=0..2007 (pivot q0 via q=+INF)

// One fused kernel:
//  grid = NMAT*NCHUNK = 256 blocks, 256 threads.
//  Each block: (1) build diag in LDS + Gershgorin bounds (bit-identical across
//  blocks of the same matrix -> no cross-block dependency), (2) one Sturm
//  count per thread at probe p = chunk*CSTRIDE + t (adjacent chunks share one
//  boundary probe, recomputed identically), (3) scatter eigenvalues: thread t
//  owns bracket (x_{p-1}, x_p]; eigen-indices k in [count(x_{p-1}), count(x_p))
//  get the bracket midpoint. Union of consecutive [c_{t-1}, c_t) ranges covers
//  every k even if counts slip +-1 (double-write is benign, no gaps).
__global__ void eval_eig_fused(const float* __restrict__ ptl,
                               float* __restrict__ out) {
    const int t  = threadIdx.x;
    const int m  = blockIdx.x >> 4;      // matrix index  (b*4 + l)
    const int ch = blockIdx.x & 15;      // chunk index
    const int b  = m >> 2;
    const int l  = m & 3;
    const float ll1 = (float)(l * (l + 1));

    __shared__ float ds[NPAD];
    __shared__ float rmn[256], rmx[256];
    __shared__ int   sc[256];

    // ---- (1) diagonal + min/max ----------------------------------------
    const float* p_row = ptl + b * RN;
    float lmin = 3.0e38f, lmax = -3.0e38f;
    for (int i = t; i < NPAD; i += 256) {
        float d;
        if (i < RN) {
            float r = 0.05f * (float)(i + 1);          // linspace(RM/RN, RM, RN)
            d = DCONST + p_row[i] + ll1 / (r * r);
            lmin = fminf(lmin, d);
            lmax = fmaxf(lmax, d);
        } else {
            d = __builtin_huge_valf();                  // pad rows: sign-neutral
        }
        ds[i] = d;
    }
    rmn[t] = lmin;
    rmx[t] = lmax;
    __syncthreads();
    for (int s = 128; s > 0; s >>= 1) {
        if (t < s) {
            rmn[t] = fminf(rmn[t], rmn[t + s]);
            rmx[t] = fmaxf(rmx[t], rmx[t + s]);
        }
        __syncthreads();
    }
    const float lo   = rmn[0] - GERSH;
    const float hi   = rmx[0] + GERSH;
    const float step = (hi - lo) / (float)(NPT + 1);

    // ---- (2) Sturm count at x_p, p = ch*CSTRIDE + t ---------------------
    const int   p = ch * CSTRIDE + t;
    const float x = lo + step * (float)(p + 1);

    float q   = __builtin_huge_valf();   // rcp(+inf)=+0 -> first iter q=d0-x
    int   cnt = 0;
    const float4* ds4 = (const float4*)ds;
    float4 A = ds4[0], B = ds4[1];

#define SITER(dv)                                                \
    {                                                            \
        float r_ = __builtin_amdgcn_rcpf(q);                     \
        q = ((dv) - x) - E2 * r_;                                \
        cnt += (int)(__float_as_uint(q) >> 31);                  \
    }

    for (int g = 0; g < NGRP; ++g) {
        float4 An = ds4[2 * g + 2];      // prefetch next group (pad keeps
        float4 Bn = ds4[2 * g + 3];      // g=250 reads in-bounds: 503 < 504)
        SITER(A.x) SITER(A.y) SITER(A.z) SITER(A.w)
        SITER(B.x) SITER(B.y) SITER(B.z) SITER(B.w)
        A = An; B = Bn;
    }
#undef SITER

    // ---- (3) scatter eigenvalues ---------------------------------------
    sc[t] = cnt;
    __syncthreads();
    float* o = out + m * RN;
    const int ccur = cnt;
    if (t > 0) {
        const int cprev = sc[t - 1];
        const float xm = x - 0.5f * step;
        for (int k = cprev; k < ccur; ++k) o[k] = xm;
    } else if (ch == 0) {
        const float xm = x - 0.5f * step;         // bracket (lo, x_0]
        for (int k = 0; k < ccur; ++k) o[k] = xm;
    }
    if (ch == NCHUNK - 1 && t == 255) {           // bracket (x_last, hi]
        const float xm = x + 0.5f * step;
        for (int k = ccur; k < RN; ++k) o[k] = xm;
    }
}

// ---------------------------------------------------------------------------
extern "C" void kernel_launch(void* const* d_in, const int* in_sizes, int n_in,
                              void* d_out, int out_size, void* d_ws, size_t ws_size,
                              hipStream_t stream) {
    const float* ptl = (const float*)d_in[0];   // (B=4, RN) f32
    float* out = (float*)d_out;                 // (4, 4, RN) f32 ascending

    eval_eig_fused<<<NMAT * NCHUNK, 256, 0, stream>>>(ptl, out);
}